// Round 13
// baseline (131.171 us; speedup 1.0000x reference)
//
#include <hip/hip_runtime.h>

typedef unsigned short u16t;
typedef unsigned int   u32t;
typedef __bf16 bf16x8 __attribute__((ext_vector_type(8)));
typedef float  f32x4  __attribute__((ext_vector_type(4)));

#define NB   64
#define DIN  1024
#define DOUT 256
#define EPS  1e-4f   // LR*LR
#define KP   68      // LDS row stride in u16 (34 dw == 2 mod 32; proven 0-conflict)
#define TP   17      // k_prep transpose-tile stride in dwords (odd => lane*17 spans banks)

#define OUT_STATE (NB*DIN*DOUT)
#define OUT_LL    (OUT_STATE + 1)
#define OUT_RR    (OUT_LL + NB*DIN)

__device__ __forceinline__ u16t f2b(float x) {
    u32t u = __builtin_bit_cast(u32t, x);
    u += 0x7FFFu + ((u >> 16) & 1u);          // RTNE
    return (u16t)(u >> 16);
}
__device__ __forceinline__ float b2f(u16t h) {
    return __builtin_bit_cast(float, ((u32t)h) << 16);
}
__device__ __forceinline__ u32t pk(u16t lo, u16t hi) {
    return (u32t)lo | ((u32t)hi << 16);
}
__device__ __forceinline__ bf16x8 ld_frag(const u16t* p) {
    uint2 lo = *(const uint2*)(p);
    uint2 hi = *(const uint2*)(p + 4);
    union { uint4 u; bf16x8 v; } x;
    x.u = make_uint4(lo.x, lo.y, hi.x, hi.y);
    return x.v;
}
__device__ __forceinline__ void st8(u16t* p, u32t a, u32t b) {
    *(uint2*)(p) = make_uint2(a, b);
}

// ============================================================
// K1 (k_prep): per 32-i chunk of one n:
//   - row moments -> ll (out); GHT[o][i] = bf16(a_i*grad[i][o]) transposed
//   - MT[p][i] = bf16(M[i][p]) transposed
//   - col partials CP (128 slots/n)
// 32-row chunk => LDS 17.4KB, VGPR<=64 via (256,8): 8 blocks/CU, 32 waves.
// LDS rows sigma-swizzled: col c4*4+c stored at row c*64+lane
//   => write bank = (lane*17 + mw) mod 32: 2-way (free).
// Dump: q-th pass, thread tid -> row q*64+(tid>>2), 16B chunk (tid&3):
//   per wave-store 16 x 64B contiguous segments; reads ~4-way max.
// grid 2048 = (32 chunks x 64 n), block 256. bid&63 == n (XCD locality).
// ============================================================
__global__ __launch_bounds__(256, 8) void k_prep(
    const float* __restrict__ grad, const float* __restrict__ M,
    const float* __restrict__ L0, float* __restrict__ out,
    u16t* __restrict__ GHT, u16t* __restrict__ MT, float* __restrict__ CP)
{
    __shared__ u32t sT[256 * TP];
    const int bid = blockIdx.x;
    const int n = bid & 63;
    const int chunk = bid >> 6;                 // 0..31
    const int tid = threadIdx.x, wave = tid >> 6, lane = tid & 63;
    const int ib = chunk * 32;
    const float* gb = grad + ((size_t)n << 18);
    const float* Mb = M + ((size_t)n << 18);

    // ---- phase 1: grad -> stats + transposed GHT tile ----
    float4 cacc = {0.f, 0.f, 0.f, 0.f};
    #pragma unroll
    for (int pr = 0; pr < 4; ++pr) {
        const int iloc = wave * 8 + 2 * pr;     // local row pair base (wave owns 8 rows)
        const int ig = ib + iloc;
        const float4 v0 = *(const float4*)(gb + (size_t)(ig    ) * 256 + lane * 4);
        const float4 v1 = *(const float4*)(gb + (size_t)(ig + 1) * 256 + lane * 4);
        float s0 = v0.x*v0.x + v0.y*v0.y + v0.z*v0.z + v0.w*v0.w;
        float s1 = v1.x*v1.x + v1.y*v1.y + v1.z*v1.z + v1.w*v1.w;
        cacc.x += v0.x*v0.x + v1.x*v1.x; cacc.y += v0.y*v0.y + v1.y*v1.y;
        cacc.z += v0.z*v0.z + v1.z*v1.z; cacc.w += v0.w*v0.w + v1.w*v1.w;
        #pragma unroll
        for (int off = 32; off; off >>= 1) { s0 += __shfl_xor(s0, off); s1 += __shfl_xor(s1, off); }
        const float l00 = L0[n * DIN + ig], l01 = L0[n * DIN + ig + 1];
        const float ll0 = fmaxf(l00, 0.5f * l00 + s0 * (0.5f / DOUT));
        const float ll1 = fmaxf(l01, 0.5f * l01 + s1 * (0.5f / DOUT));
        const float a0 = rsqrtf(sqrtf(ll0)), a1 = rsqrtf(sqrtf(ll1));
        if (lane == 0) {
            out[OUT_LL + n * DIN + ig]     = ll0;
            out[OUT_LL + n * DIN + ig + 1] = ll1;
        }
        const int mw = wave * 4 + pr;           // word index 0..15
        // col = 4*lane + c  ->  LDS row c*64 + lane
        sT[(0*64 + lane) * TP + mw] = pk(f2b(v0.x*a0), f2b(v1.x*a1));
        sT[(1*64 + lane) * TP + mw] = pk(f2b(v0.y*a0), f2b(v1.y*a1));
        sT[(2*64 + lane) * TP + mw] = pk(f2b(v0.z*a0), f2b(v1.z*a1));
        sT[(3*64 + lane) * TP + mw] = pk(f2b(v0.w*a0), f2b(v1.w*a1));
    }
    const int slot = chunk * 4 + wave;          // 0..127
    *(float4*)(CP + ((size_t)(n * 128 + slot)) * 256 + lane * 4) = cacc;
    __syncthreads();
    {   // coalesced dump of GHT rows (64B per row)
        u16t* G = GHT + ((size_t)n << 18);
        #pragma unroll
        for (int q = 0; q < 4; ++q) {
            const int ro = q * 64 + (tid >> 2);
            const int sig = (ro & 3) * 64 + (ro >> 2);
            const u32t* src = &sT[sig * TP + (tid & 3) * 4];
            uint4 v = make_uint4(src[0], src[1], src[2], src[3]);
            *(uint4*)(G + (size_t)ro * 1024 + ib + (tid & 3) * 8) = v;
        }
    }
    __syncthreads();
    // ---- phase 2: M -> transposed MT tile ----
    #pragma unroll
    for (int pr = 0; pr < 4; ++pr) {
        const int iloc = wave * 8 + 2 * pr;
        const int ig = ib + iloc;
        const float4 v0 = *(const float4*)(Mb + (size_t)(ig    ) * 256 + lane * 4);
        const float4 v1 = *(const float4*)(Mb + (size_t)(ig + 1) * 256 + lane * 4);
        const int mw = wave * 4 + pr;
        sT[(0*64 + lane) * TP + mw] = pk(f2b(v0.x), f2b(v1.x));
        sT[(1*64 + lane) * TP + mw] = pk(f2b(v0.y), f2b(v1.y));
        sT[(2*64 + lane) * TP + mw] = pk(f2b(v0.z), f2b(v1.z));
        sT[(3*64 + lane) * TP + mw] = pk(f2b(v0.w), f2b(v1.w));
    }
    __syncthreads();
    {   // coalesced dump of MT rows
        u16t* Mo = MT + ((size_t)n << 18);
        #pragma unroll
        for (int q = 0; q < 4; ++q) {
            const int ro = q * 64 + (tid >> 2);
            const int sig = (ro & 3) * 64 + (ro >> 2);
            const u32t* src = &sT[sig * TP + (tid & 3) * 4];
            uint4 v = make_uint4(src[0], src[1], src[2], src[3]);
            *(uint4*)(Mo + (size_t)ro * 1024 + ib + (tid & 3) * 8) = v;
        }
    }
}

// ============================================================
// K2: reduce 128 col partials -> rr (out), BS = rr^-1/4 ; copy state
// ============================================================
__global__ __launch_bounds__(256) void k_cols(
    const float* __restrict__ R0, const float* __restrict__ state,
    float* __restrict__ out, float* __restrict__ BS, const float* __restrict__ CP)
{
    const int n = blockIdx.x, o = threadIdx.x;
    const float* cp = CP + (size_t)n * 128 * 256 + o;
    float s = 0.f;
    #pragma unroll 8
    for (int k = 0; k < 128; ++k) s += cp[k * 256];
    const float r0 = R0[n * DOUT + o];
    const float rr = fmaxf(r0, 0.5f * r0 + s * (0.5f / DIN));
    out[OUT_RR + n * DOUT + o] = rr;
    BS[n * DOUT + o] = rsqrtf(sqrtf(rr));
    if (n == 0 && o == 0) out[OUT_STATE] = state[0];
}

// ============================================================
// G1 (k_T): TT[o][p] = b[o] * sum_i GHT[o][i] * MT[p][i]   (pure NT GEMM)
// Coalesced row reads, natural st8 staging (proven 0-conflict).
// tile 128o x 64p, BK=64 (16 chunks). grid 512 = (8 tiles x 64 n).
// ============================================================
__global__ __launch_bounds__(256, 4) void k_T(
    const u16t* __restrict__ GHT, const u16t* __restrict__ MT,
    const float* __restrict__ BS, u16t* __restrict__ TT)
{
    __shared__ u16t sA[128 * KP];   // [o][i]
    __shared__ u16t sB[64 * KP];    // [p][i]
    const int bid = blockIdx.x;
    const int n = bid & 63;
    const int tile = bid >> 6;                  // 0..7
    const int o0 = (tile & 1) * 128, p0 = (tile >> 1) * 64;
    const int t = threadIdx.x, lane = t & 63, w = t >> 6;
    const int wr = w >> 1, wc = w & 1, t16 = lane & 15, g4 = lane >> 4;
    const u16t* GA = GHT + ((size_t)n << 18);
    const u16t* GB = MT + ((size_t)n << 18);
    uint4 rA[4], rB[2];
    f32x4 acc[4][2] = {};

#define T_LOAD(ch) { const int ib_ = (ch) * 64; \
    _Pragma("unroll") for (int j = 0; j < 4; ++j) { \
        const int s = j * 256 + t, row = s >> 3, c8 = (s & 7) * 8; \
        rA[j] = *(const uint4*)(GA + (size_t)(o0 + row) * 1024 + ib_ + c8); } \
    _Pragma("unroll") for (int j = 0; j < 2; ++j) { \
        const int s = j * 256 + t, row = s >> 3, c8 = (s & 7) * 8; \
        rB[j] = *(const uint4*)(GB + (size_t)(p0 + row) * 1024 + ib_ + c8); } }

    T_LOAD(0);
    for (int ch = 0; ch < 16; ++ch) {
        __syncthreads();
        #pragma unroll
        for (int j = 0; j < 4; ++j) {
            const int s = j * 256 + t, row = s >> 3, c8 = (s & 7) * 8;
            st8(sA + row * KP + c8,     rA[j].x, rA[j].y);
            st8(sA + row * KP + c8 + 4, rA[j].z, rA[j].w);
        }
        #pragma unroll
        for (int j = 0; j < 2; ++j) {
            const int s = j * 256 + t, row = s >> 3, c8 = (s & 7) * 8;
            st8(sB + row * KP + c8,     rB[j].x, rB[j].y);
            st8(sB + row * KP + c8 + 4, rB[j].z, rB[j].w);
        }
        __syncthreads();
        if (ch < 15) T_LOAD(ch + 1);            // overlaps MFMA phase
        #pragma unroll
        for (int kb = 0; kb < 2; ++kb) {
            const int ko = kb * 32 + g4 * 8;
            bf16x8 fa[4], fb[2];
            #pragma unroll
            for (int fm = 0; fm < 4; ++fm)
                fa[fm] = ld_frag(sA + (wr*64 + fm*16 + t16) * KP + ko);
            #pragma unroll
            for (int fn = 0; fn < 2; ++fn)
                fb[fn] = ld_frag(sB + (wc*32 + fn*16 + t16) * KP + ko);
            #pragma unroll
            for (int fm = 0; fm < 4; ++fm)
                #pragma unroll
                for (int fn = 0; fn < 2; ++fn)
                    acc[fm][fn] = __builtin_amdgcn_mfma_f32_16x16x32_bf16(fa[fm], fb[fn], acc[fm][fn], 0, 0, 0);
        }
    }
    const float* bs = BS + n * DOUT;
    u16t* TTn = TT + ((size_t)n << 16);
    #pragma unroll
    for (int fm = 0; fm < 4; ++fm)
        #pragma unroll
        for (int fn = 0; fn < 2; ++fn) {
            const int p = p0 + wc*32 + fn*16 + t16;
            #pragma unroll
            for (int r = 0; r < 4; ++r) {
                const int o = o0 + wr*64 + fm*16 + g4*4 + r;
                TTn[o * 256 + p] = f2b(acc[fm][fn][r] * bs[o]);
            }
        }
}

// ============================================================
// G2 (k_fuse): Mnew[i][o] = M[i][o] + EPS*( sum_p M[i][p]*TT[o][p]
//                                           - b_o * a_i * grad[i][o] )
// a_i = ll^-1/4 re-derived from ll output (staged per block).
// tile 128i x 128o, K=256 (4 chunks). grid 1024 = (16 tiles x 64 n).
// ============================================================
__global__ __launch_bounds__(256, 3) void k_fuse(
    const float* __restrict__ M, const float* __restrict__ grad,
    const float* __restrict__ BS, const u16t* __restrict__ TT,
    float* __restrict__ out)
{
    __shared__ u16t sA[128 * KP];   // [i][p]
    __shared__ u16t sB[128 * KP];   // [o][p]
    __shared__ float sa_[128];      // a_i for this i-tile
    const int bid = blockIdx.x;
    const int n = bid & 63;
    const int tile = bid >> 6;                  // 0..15: 8 i-tiles x 2 o-tiles
    const int i0 = (tile & 7) * 128, o0 = (tile >> 3) * 128;
    const int t = threadIdx.x, lane = t & 63, w = t >> 6;
    const int wr = w >> 1, wc = w & 1, t16 = lane & 15, g4 = lane >> 4;
    const float* Mn = M + ((size_t)n << 18);
    const float* Gr = grad + ((size_t)n << 18);
    const u16t* TTn = TT + ((size_t)n << 16);
    if (t < 128) {
        const float ll = out[OUT_LL + n * DIN + i0 + t];
        sa_[t] = rsqrtf(sqrtf(ll));
    }
    float4 rMa[8];
    uint4  rTb[4];
    f32x4 acc[4][4] = {};

#define FU_LOAD(ch) { const int pb_ = (ch) * 64; \
    _Pragma("unroll") for (int j = 0; j < 8; ++j) { \
        const int s = j * 256 + t, row = s >> 4, c4 = (s & 15) * 4; \
        rMa[j] = *(const float4*)(Mn + (size_t)(i0 + row) * 256 + pb_ + c4); } \
    _Pragma("unroll") for (int j = 0; j < 4; ++j) { \
        const int s = j * 256 + t, row = s >> 3, c8 = (s & 7) * 8; \
        rTb[j] = *(const uint4*)(TTn + (size_t)(o0 + row) * 256 + pb_ + c8); } }

    FU_LOAD(0);
    for (int ch = 0; ch < 4; ++ch) {
        __syncthreads();
        #pragma unroll
        for (int j = 0; j < 8; ++j) {
            const int s = j * 256 + t, row = s >> 4, c4 = (s & 15) * 4;
            const float4 v = rMa[j];
            ushort4 h = { f2b(v.x), f2b(v.y), f2b(v.z), f2b(v.w) };
            *(ushort4*)(sA + row * KP + c4) = h;
        }
        #pragma unroll
        for (int j = 0; j < 4; ++j) {
            const int s = j * 256 + t, row = s >> 3, c8 = (s & 7) * 8;
            st8(sB + row * KP + c8,     rTb[j].x, rTb[j].y);
            st8(sB + row * KP + c8 + 4, rTb[j].z, rTb[j].w);
        }
        __syncthreads();
        if (ch < 3) FU_LOAD(ch + 1);
        #pragma unroll
        for (int kb = 0; kb < 2; ++kb) {
            const int ko = kb * 32 + g4 * 8;
            bf16x8 fa[4], fb[4];
            #pragma unroll
            for (int fm = 0; fm < 4; ++fm)
                fa[fm] = ld_frag(sA + (wr*64 + fm*16 + t16) * KP + ko);
            #pragma unroll
            for (int fn = 0; fn < 4; ++fn)
                fb[fn] = ld_frag(sB + (wc*64 + fn*16 + t16) * KP + ko);
            #pragma unroll
            for (int fm = 0; fm < 4; ++fm)
                #pragma unroll
                for (int fn = 0; fn < 4; ++fn)
                    acc[fm][fn] = __builtin_amdgcn_mfma_f32_16x16x32_bf16(fa[fm], fb[fn], acc[fm][fn], 0, 0, 0);
        }
    }
    const float* bs = BS + n * DOUT;
    float* outn = out + ((size_t)n << 18);
    #pragma unroll
    for (int fm = 0; fm < 4; ++fm)
        #pragma unroll
        for (int fn = 0; fn < 4; ++fn) {
            const int o = o0 + wc*64 + fn*16 + t16;
            const float bo = bs[o];
            #pragma unroll
            for (int r = 0; r < 4; ++r) {
                const int il = wr*64 + fm*16 + g4*4 + r;
                const int i = i0 + il;
                const size_t idx = (size_t)i * 256 + o;
                outn[idx] = Mn[idx] + EPS * (acc[fm][fn][r] - bo * sa_[il] * Gr[idx]);
            }
        }
}

extern "C" void kernel_launch(void* const* d_in, const int* in_sizes, int n_in,
                              void* d_out, int out_size, void* d_ws, size_t ws_size,
                              hipStream_t stream) {
    const float* grad  = (const float*)d_in[0];
    const float* M     = (const float*)d_in[1];
    const float* state = (const float*)d_in[2];
    const float* L0    = (const float*)d_in[3];
    const float* R0    = (const float*)d_in[4];
    float* out = (float*)d_out;
    char* wsb = (char*)d_ws;

    // region map (~80.1 MB; <= 85 proven safe):
    u16t* GHT = (u16t*)(wsb);                          // [0,32MB)   GHT[n][o][i]
    u16t* MT  = (u16t*)(wsb + ((size_t)32 << 20));     // [32,64MB)  MT[n][p][i]
    u16t* TT  = (u16t*)(wsb + ((size_t)64 << 20));     // [64,72MB)  TT[n][o][p]
    float* CP = (float*)(wsb + ((size_t)72 << 20));    // [72,80MB)  CP[n][128][256]
    float* BS = (float*)(wsb + ((size_t)80 << 20));    // 64KB

    k_prep <<<2048, 256, 0, stream>>>(grad, M, L0, out, GHT, MT, CP);
    k_cols <<<64,   256, 0, stream>>>(R0, state, out, BS, CP);
    k_T    <<<512,  256, 0, stream>>>(GHT, MT, BS, TT);
    k_fuse <<<1024, 256, 0, stream>>>(M, grad, BS, TT, out);
}

// Round 14
// 102.931 us; speedup vs baseline: 1.2744x; 1.2744x over previous
//
#include <hip/hip_runtime.h>

typedef unsigned short u16t;
typedef unsigned int   u32t;
typedef __bf16 bf16x8 __attribute__((ext_vector_type(8)));
typedef float  f32x4  __attribute__((ext_vector_type(4)));

#define NB   64
#define DIN  1024
#define DOUT 256
#define EPS  1e-4f   // LR*LR
#define KP   68      // LDS row stride in u16 (34 dw == 2 mod 32; proven 0-conflict)

#define OUT_STATE (NB*DIN*DOUT)
#define OUT_LL    (OUT_STATE + 1)
#define OUT_RR    (OUT_LL + NB*DIN)

__device__ __forceinline__ u16t f2b(float x) {
    u32t u = __builtin_bit_cast(u32t, x);
    u += 0x7FFFu + ((u >> 16) & 1u);          // RTNE
    return (u16t)(u >> 16);
}
__device__ __forceinline__ float b2f(u16t h) {
    return __builtin_bit_cast(float, ((u32t)h) << 16);
}
__device__ __forceinline__ bf16x8 ld_frag(const u16t* p) {
    uint2 lo = *(const uint2*)(p);
    uint2 hi = *(const uint2*)(p + 4);
    union { uint4 u; bf16x8 v; } x;
    x.u = make_uint4(lo.x, lo.y, hi.x, hi.y);
    return x.v;
}
__device__ __forceinline__ void st8(u16t* p, u32t a, u32t b) {
    *(uint2*)(p) = make_uint2(a, b);
}

// ============================================================
// K1 (k_prep): stats only, no LDS (R5-proven shape).
//   row moments -> ll (out), AS = ll^-1/4, col partials CP (128 slots/n).
// grid 2048 = (32 chunks x 64 n), block 256 (4 waves x 8 rows).
// ============================================================
__global__ __launch_bounds__(256) void k_prep(
    const float* __restrict__ grad, const float* __restrict__ L0,
    float* __restrict__ out, float* __restrict__ AS, float* __restrict__ CP)
{
    const int bid = blockIdx.x;
    const int n = bid & 63;
    const int chunk = bid >> 6;                 // 0..31
    const int wave = threadIdx.x >> 6, lane = threadIdx.x & 63;
    const float* gb = grad + ((size_t)n << 18);

    float4 cacc = {0.f, 0.f, 0.f, 0.f};
    const int i0 = chunk * 32 + wave * 8;
    #pragma unroll
    for (int r = 0; r < 8; ++r) {
        const int i = i0 + r;
        const float4 v = *(const float4*)(gb + (size_t)i * 256 + lane * 4);
        float s = v.x*v.x + v.y*v.y + v.z*v.z + v.w*v.w;
        cacc.x += v.x*v.x; cacc.y += v.y*v.y; cacc.z += v.z*v.z; cacc.w += v.w*v.w;
        #pragma unroll
        for (int off = 32; off; off >>= 1) s += __shfl_xor(s, off);
        const float l0 = L0[n * DIN + i];
        const float ll = fmaxf(l0, 0.5f * l0 + s * (0.5f / DOUT));
        if (lane == 0) {
            out[OUT_LL + n * DIN + i] = ll;
            AS[n * DIN + i] = rsqrtf(sqrtf(ll));
        }
    }
    const int slot = chunk * 4 + wave;          // 0..127
    *(float4*)(CP + ((size_t)(n * 128 + slot)) * 256 + lane * 4) = cacc;
}

// ============================================================
// K2: reduce 128 col partials -> rr (out), BS = rr^-1/4 ; copy state
// ============================================================
__global__ __launch_bounds__(256) void k_cols(
    const float* __restrict__ R0, const float* __restrict__ state,
    float* __restrict__ out, float* __restrict__ BS, const float* __restrict__ CP)
{
    const int n = blockIdx.x, o = threadIdx.x;
    const float* cp = CP + (size_t)n * 128 * 256 + o;
    float s = 0.f;
    #pragma unroll 8
    for (int k = 0; k < 128; ++k) s += cp[k * 256];
    const float r0 = R0[n * DOUT + o];
    const float rr = fmaxf(r0, 0.5f * r0 + s * (0.5f / DIN));
    out[OUT_RR + n * DOUT + o] = rr;
    BS[n * DOUT + o] = rsqrtf(sqrtf(rr));
    if (n == 0 && o == 0) out[OUT_STATE] = state[0];
}

// ============================================================
// G1 (k_T): TT[o][p] = b[o] * sum_i (a_i*grad[i][o]) * M[i][p]
// Direct fp32 operands; R3-proven transpose staging: per row il, lanes
// read a contiguous 256B column span (coalesced), scalar LDS writes at
// KP=68 (bank = 2*lane -> 2-way, free). a_i wave-uniform from AS.
// tile 128o x 64p, BK=64 (16 chunks). grid 512 = (8 tiles x 64 n).
// ============================================================
__global__ __launch_bounds__(256, 4) void k_T(
    const float* __restrict__ grad, const float* __restrict__ M,
    const float* __restrict__ AS, const float* __restrict__ BS,
    u16t* __restrict__ TT)
{
    __shared__ u16t sA[128 * KP];   // [o][i]
    __shared__ u16t sB[64 * KP];    // [p][i]
    const int bid = blockIdx.x;
    const int n = bid & 63;
    const int tile = bid >> 6;                  // 0..7: 2 o-tiles x 4 p-tiles
    const int o0 = (tile & 1) * 128, p0 = (tile >> 1) * 64;
    const int t = threadIdx.x, lane = t & 63, w = t >> 6;
    const int wr = w >> 1, wc = w & 1, t16 = lane & 15, g4 = lane >> 4;
    const float* Gn = grad + ((size_t)n << 18);
    const float* Mn = M + ((size_t)n << 18);
    const float* An = AS + n * DIN;
    f32x4 acc[4][2] = {};

    for (int ch = 0; ch < 16; ++ch) {
        const int ib = ch * 64;
        __syncthreads();
        #pragma unroll
        for (int r = 0; r < 16; ++r) {
            const int il = w * 16 + r;
            const int ig = ib + il;
            const float a = An[ig];
            const float* gsrc = Gn + (size_t)ig * 256 + o0;
            const float* msrc = Mn + (size_t)ig * 256 + p0;
            sA[(size_t)lane * KP + il]        = f2b(gsrc[lane] * a);
            sA[(size_t)(lane + 64) * KP + il] = f2b(gsrc[lane + 64] * a);
            sB[(size_t)lane * KP + il]        = f2b(msrc[lane]);
        }
        __syncthreads();
        #pragma unroll
        for (int kb = 0; kb < 2; ++kb) {
            const int ko = kb * 32 + g4 * 8;
            bf16x8 fa[4], fb[2];
            #pragma unroll
            for (int fm = 0; fm < 4; ++fm)
                fa[fm] = ld_frag(sA + (wr*64 + fm*16 + t16) * KP + ko);
            #pragma unroll
            for (int fn = 0; fn < 2; ++fn)
                fb[fn] = ld_frag(sB + (wc*32 + fn*16 + t16) * KP + ko);
            #pragma unroll
            for (int fm = 0; fm < 4; ++fm)
                #pragma unroll
                for (int fn = 0; fn < 2; ++fn)
                    acc[fm][fn] = __builtin_amdgcn_mfma_f32_16x16x32_bf16(fa[fm], fb[fn], acc[fm][fn], 0, 0, 0);
        }
    }
    const float* bs = BS + n * DOUT;
    u16t* TTn = TT + ((size_t)n << 16);
    #pragma unroll
    for (int fm = 0; fm < 4; ++fm)
        #pragma unroll
        for (int fn = 0; fn < 2; ++fn) {
            const int p = p0 + wc*32 + fn*16 + t16;
            #pragma unroll
            for (int r = 0; r < 4; ++r) {
                const int o = o0 + wr*64 + fm*16 + g4*4 + r;
                TTn[o * 256 + p] = f2b(acc[fm][fn][r] * bs[o]);
            }
        }
}

// ============================================================
// G2 (k_fuse): Mnew[i][o] = M[i][o] + EPS*( sum_p M[i][p]*TT[o][p]
//                                           - b_o * a_i * grad[i][o] )
// a_i re-derived from ll output (staged per block).
// tile 128i x 128o, K=256 (4 chunks). grid 1024 = (16 tiles x 64 n).
// ============================================================
__global__ __launch_bounds__(256, 3) void k_fuse(
    const float* __restrict__ M, const float* __restrict__ grad,
    const float* __restrict__ BS, const u16t* __restrict__ TT,
    float* __restrict__ out)
{
    __shared__ u16t sA[128 * KP];   // [i][p]
    __shared__ u16t sB[128 * KP];   // [o][p]
    __shared__ float sa_[128];      // a_i for this i-tile
    const int bid = blockIdx.x;
    const int n = bid & 63;
    const int tile = bid >> 6;                  // 0..15: 8 i-tiles x 2 o-tiles
    const int i0 = (tile & 7) * 128, o0 = (tile >> 3) * 128;
    const int t = threadIdx.x, lane = t & 63, w = t >> 6;
    const int wr = w >> 1, wc = w & 1, t16 = lane & 15, g4 = lane >> 4;
    const float* Mn = M + ((size_t)n << 18);
    const float* Gr = grad + ((size_t)n << 18);
    const u16t* TTn = TT + ((size_t)n << 16);
    if (t < 128) {
        const float ll = out[OUT_LL + n * DIN + i0 + t];
        sa_[t] = rsqrtf(sqrtf(ll));
    }
    float4 rMa[8];
    uint4  rTb[4];
    f32x4 acc[4][4] = {};

#define FU_LOAD(ch) { const int pb_ = (ch) * 64; \
    _Pragma("unroll") for (int j = 0; j < 8; ++j) { \
        const int s = j * 256 + t, row = s >> 4, c4 = (s & 15) * 4; \
        rMa[j] = *(const float4*)(Mn + (size_t)(i0 + row) * 256 + pb_ + c4); } \
    _Pragma("unroll") for (int j = 0; j < 4; ++j) { \
        const int s = j * 256 + t, row = s >> 3, c8 = (s & 7) * 8; \
        rTb[j] = *(const uint4*)(TTn + (size_t)(o0 + row) * 256 + pb_ + c8); } }

    FU_LOAD(0);
    for (int ch = 0; ch < 4; ++ch) {
        __syncthreads();
        #pragma unroll
        for (int j = 0; j < 8; ++j) {
            const int s = j * 256 + t, row = s >> 4, c4 = (s & 15) * 4;
            const float4 v = rMa[j];
            ushort4 h = { f2b(v.x), f2b(v.y), f2b(v.z), f2b(v.w) };
            *(ushort4*)(sA + row * KP + c4) = h;
        }
        #pragma unroll
        for (int j = 0; j < 4; ++j) {
            const int s = j * 256 + t, row = s >> 3, c8 = (s & 7) * 8;
            st8(sB + row * KP + c8,     rTb[j].x, rTb[j].y);
            st8(sB + row * KP + c8 + 4, rTb[j].z, rTb[j].w);
        }
        __syncthreads();
        if (ch < 3) FU_LOAD(ch + 1);
        #pragma unroll
        for (int kb = 0; kb < 2; ++kb) {
            const int ko = kb * 32 + g4 * 8;
            bf16x8 fa[4], fb[4];
            #pragma unroll
            for (int fm = 0; fm < 4; ++fm)
                fa[fm] = ld_frag(sA + (wr*64 + fm*16 + t16) * KP + ko);
            #pragma unroll
            for (int fn = 0; fn < 4; ++fn)
                fb[fn] = ld_frag(sB + (wc*64 + fn*16 + t16) * KP + ko);
            #pragma unroll
            for (int fm = 0; fm < 4; ++fm)
                #pragma unroll
                for (int fn = 0; fn < 4; ++fn)
                    acc[fm][fn] = __builtin_amdgcn_mfma_f32_16x16x32_bf16(fa[fm], fb[fn], acc[fm][fn], 0, 0, 0);
        }
    }
    const float* bs = BS + n * DOUT;
    float* outn = out + ((size_t)n << 18);
    #pragma unroll
    for (int fm = 0; fm < 4; ++fm)
        #pragma unroll
        for (int fn = 0; fn < 4; ++fn) {
            const int o = o0 + wc*64 + fn*16 + t16;
            const float bo = bs[o];
            #pragma unroll
            for (int r = 0; r < 4; ++r) {
                const int il = wr*64 + fm*16 + g4*4 + r;
                const int i = i0 + il;
                const size_t idx = (size_t)i * 256 + o;
                outn[idx] = Mn[idx] + EPS * (acc[fm][fn][r] - bo * sa_[il] * Gr[idx]);
            }
        }
}

extern "C" void kernel_launch(void* const* d_in, const int* in_sizes, int n_in,
                              void* d_out, int out_size, void* d_ws, size_t ws_size,
                              hipStream_t stream) {
    const float* grad  = (const float*)d_in[0];
    const float* M     = (const float*)d_in[1];
    const float* state = (const float*)d_in[2];
    const float* L0    = (const float*)d_in[3];
    const float* R0    = (const float*)d_in[4];
    float* out = (float*)d_out;
    char* wsb = (char*)d_ws;

    // region map (~17.5 MB):
    u16t*  TT = (u16t*)(wsb);                          // [0,8MB)    TT[n][o][p]
    float* CP = (float*)(wsb + ((size_t)8 << 20));     // [8,16MB)   CP[n][128][256]
    float* AS = (float*)(wsb + ((size_t)16 << 20));    // [16,16.25) AS[n][1024]
    float* BS = (float*)(wsb + ((size_t)17 << 20));    // 64KB

    k_prep <<<2048, 256, 0, stream>>>(grad, L0, out, AS, CP);
    k_cols <<<64,   256, 0, stream>>>(R0, state, out, BS, CP);
    k_T    <<<512,  256, 0, stream>>>(grad, M, AS, BS, TT);
    k_fuse <<<1024, 256, 0, stream>>>(M, grad, BS, TT, out);
}